// Round 1
// baseline (285.129 us; speedup 1.0000x reference)
//
#include <hip/hip_runtime.h>
#include <hip/hip_bf16.h>
#include <math.h>

#define CIN 256
#define COUT 512

// ---------------------------------------------------------------------------
// init: inv5[n5] = -1, inv4[n4] = -1
// ---------------------------------------------------------------------------
__global__ __launch_bounds__(256) void init_kernel(int* inv5, int n5, int* inv4, int n4) {
    int i = blockIdx.x * blockDim.x + threadIdx.x;
    if (i < n5) inv5[i] = -1;
    if (i < n4) inv4[i] = -1;
}

// ---------------------------------------------------------------------------
// scatter inverse maps: inv5[idx5[i]] = i  (child i lives at level-5 slot idx5[i])
//                       inv4[idx4[g]] = g
// ---------------------------------------------------------------------------
__global__ __launch_bounds__(256) void scatter_inv_kernel(const int* __restrict__ idx5, int n_i5,
                                                          const int* __restrict__ idx4, int n_i4,
                                                          int* __restrict__ inv5, int* __restrict__ inv4) {
    int i = blockIdx.x * blockDim.x + threadIdx.x;
    if (i < n_i5) inv5[idx5[i]] = i;
    if (i < n_i4) inv4[idx4[i]] = i;
}

// ---------------------------------------------------------------------------
// Fused double max-pool.
// For depth-4 group g (one per idx4 entry), level-5 slots 8g..8g+7 hold either
// pool1 result y1[i] (i = inv5[slot] >= 0, y1[i] = max over data rows 8i..8i+7)
// or zero (empty slot -> the max gets clamped at 0).
// One wave (64 lanes) per group: lane q handles columns 4q..4q+3.
// Reads each data row exactly once -> 512 MiB total, coalesced float4.
// ---------------------------------------------------------------------------
__global__ __launch_bounds__(256) void pool2_kernel(const float* __restrict__ data,
                                                    const int* __restrict__ inv5,
                                                    float* __restrict__ P, int G2) {
    int t = blockIdx.x * blockDim.x + threadIdx.x;
    int g = t >> 6;          // group (uniform within a wave)
    int q = t & 63;          // column quad
    if (g >= G2) return;

    float4 acc = make_float4(-INFINITY, -INFINITY, -INFINITY, -INFINITY);
    bool any_empty = false;

    #pragma unroll
    for (int s = 0; s < 8; ++s) {
        int i = inv5[g * 8 + s];          // wave-uniform branch
        if (i >= 0) {
            const float* base = data + (size_t)i * 8 * CIN + q * 4;
            #pragma unroll
            for (int r = 0; r < 8; ++r) {
                float4 v = *reinterpret_cast<const float4*>(base + (size_t)r * CIN);
                acc.x = fmaxf(acc.x, v.x);
                acc.y = fmaxf(acc.y, v.y);
                acc.z = fmaxf(acc.z, v.z);
                acc.w = fmaxf(acc.w, v.w);
            }
        } else {
            any_empty = true;
        }
    }
    if (any_empty) {   // zero rows participate in the second max
        acc.x = fmaxf(acc.x, 0.f);
        acc.y = fmaxf(acc.y, 0.f);
        acc.z = fmaxf(acc.z, 0.f);
        acc.w = fmaxf(acc.w, 0.f);
    }
    *reinterpret_cast<float4*>(&P[(size_t)g * CIN + q * 4]) = acc;
}

// ---------------------------------------------------------------------------
// fp32 GEMM: H[m][n] = sum_k P[m][k] * W[n][k]   (M x 256) @ (512 x 256)^T
// 64x64 tile per block, 256 threads, 4x4 accumulators/thread.
// LDS stored K-major (As[k][m]) so the inner loop uses ds_read_b128.
// ---------------------------------------------------------------------------
#define BM 64
#define BN 64
#define BK 16
#define LDST 68   // padded stride: write-phase bank conflicts 4-way -> 2-way (free)

__global__ __launch_bounds__(256) void gemm_kernel(const float* __restrict__ A,
                                                   const float* __restrict__ B,
                                                   float* __restrict__ H, int M) {
    __shared__ float As[BK][LDST];
    __shared__ float Bs[BK][LDST];

    int t = threadIdx.x;
    int m0 = blockIdx.x * BM;
    int n0 = blockIdx.y * BN;
    int tx = t & 15;          // n-direction
    int ty = t >> 4;          // m-direction

    int lm = t >> 2;          // 0..63  : row within tile for loads
    int lk = (t & 3) * 4;     // 0,4,8,12

    float acc[4][4];
    #pragma unroll
    for (int i = 0; i < 4; ++i)
        #pragma unroll
        for (int j = 0; j < 4; ++j) acc[i][j] = 0.f;

    for (int k0 = 0; k0 < CIN; k0 += BK) {
        float4 a = *reinterpret_cast<const float4*>(&A[(size_t)(m0 + lm) * CIN + k0 + lk]);
        float4 b = *reinterpret_cast<const float4*>(&B[(size_t)(n0 + lm) * CIN + k0 + lk]);
        As[lk + 0][lm] = a.x; As[lk + 1][lm] = a.y; As[lk + 2][lm] = a.z; As[lk + 3][lm] = a.w;
        Bs[lk + 0][lm] = b.x; Bs[lk + 1][lm] = b.y; Bs[lk + 2][lm] = b.z; Bs[lk + 3][lm] = b.w;
        __syncthreads();

        #pragma unroll
        for (int k = 0; k < BK; ++k) {
            float4 av = *reinterpret_cast<const float4*>(&As[k][ty * 4]);
            float4 bv = *reinterpret_cast<const float4*>(&Bs[k][tx * 4]);
            float a_[4] = {av.x, av.y, av.z, av.w};
            float b_[4] = {bv.x, bv.y, bv.z, bv.w};
            #pragma unroll
            for (int i = 0; i < 4; ++i)
                #pragma unroll
                for (int j = 0; j < 4; ++j)
                    acc[i][j] = fmaf(a_[i], b_[j], acc[i][j]);
        }
        __syncthreads();
    }

    #pragma unroll
    for (int i = 0; i < 4; ++i) {
        float4 r = make_float4(acc[i][0], acc[i][1], acc[i][2], acc[i][3]);
        *reinterpret_cast<float4*>(&H[(size_t)(m0 + ty * 4 + i) * COUT + n0 + tx * 4]) = r;
    }
}

// ---------------------------------------------------------------------------
// Deterministic column stats, stage 1: per-block partial sum / sumsq.
// partial[b][0..511] = sum, partial[b][512..1023] = sumsq
// ---------------------------------------------------------------------------
__global__ __launch_bounds__(256) void stats_partial_kernel(const float* __restrict__ H,
                                                            int rows_per_block,
                                                            float* __restrict__ partial) {
    int b = blockIdx.x;
    int c0 = threadIdx.x * 2;
    float s0 = 0.f, s1 = 0.f, q0 = 0.f, q1 = 0.f;
    size_t r0 = (size_t)b * rows_per_block;
    for (int r = 0; r < rows_per_block; ++r) {
        float2 v = *reinterpret_cast<const float2*>(&H[(r0 + r) * COUT + c0]);
        s0 += v.x; q0 = fmaf(v.x, v.x, q0);
        s1 += v.y; q1 = fmaf(v.y, v.y, q1);
    }
    float* pb = partial + (size_t)b * 1024;
    pb[c0]       = s0;
    pb[c0 + 1]   = s1;
    pb[512 + c0]     = q0;
    pb[512 + c0 + 1] = q1;
}

// ---------------------------------------------------------------------------
// Stage 2: reduce partials, compute BN scale/shift per column.
// mean over the FULL padded row count (zeros contribute 0 to sums).
// ---------------------------------------------------------------------------
__global__ __launch_bounds__(256) void bn_finalize_kernel(const float* __restrict__ partial, int nparts,
                                                          const float* __restrict__ gamma,
                                                          const float* __restrict__ beta,
                                                          float* __restrict__ scale,
                                                          float* __restrict__ shift,
                                                          float invN) {
    int c = blockIdx.x * blockDim.x + threadIdx.x;
    if (c >= COUT) return;
    float s = 0.f, q = 0.f;
    for (int p = 0; p < nparts; ++p) {
        s += partial[(size_t)p * 1024 + c];
        q += partial[(size_t)p * 1024 + 512 + c];
    }
    float mean = s * invN;
    float var  = fmaf(q, invN, -mean * mean);
    float inv  = rsqrtf(var + 1e-5f);
    float sc   = gamma[c] * inv;
    scale[c] = sc;
    shift[c] = fmaf(-mean, sc, beta[c]);
}

// ---------------------------------------------------------------------------
// Final: out[m] = relu(H[inv4[m]] * scale + shift), or relu(shift) for empty rows.
// ---------------------------------------------------------------------------
__global__ __launch_bounds__(256) void out_kernel(const float* __restrict__ H,
                                                  const int* __restrict__ inv4,
                                                  const float* __restrict__ scale,
                                                  const float* __restrict__ shift,
                                                  float* __restrict__ out, int rows) {
    int t = blockIdx.x * blockDim.x + threadIdx.x;
    int m = t >> 7;           // row
    int q = t & 127;          // column quad (512/4)
    if (m >= rows) return;
    int c = q * 4;
    int j = inv4[m];
    float4 sc = *reinterpret_cast<const float4*>(&scale[c]);
    float4 sh = *reinterpret_cast<const float4*>(&shift[c]);
    float4 r;
    if (j >= 0) {
        float4 h = *reinterpret_cast<const float4*>(&H[(size_t)j * COUT + c]);
        r.x = fmaxf(fmaf(h.x, sc.x, sh.x), 0.f);
        r.y = fmaxf(fmaf(h.y, sc.y, sh.y), 0.f);
        r.z = fmaxf(fmaf(h.z, sc.z, sh.z), 0.f);
        r.w = fmaxf(fmaf(h.w, sc.w, sh.w), 0.f);
    } else {
        r.x = fmaxf(sh.x, 0.f);
        r.y = fmaxf(sh.y, 0.f);
        r.z = fmaxf(sh.z, 0.f);
        r.w = fmaxf(sh.w, 0.f);
    }
    *reinterpret_cast<float4*>(&out[(size_t)m * COUT + c]) = r;
}

// ---------------------------------------------------------------------------
extern "C" void kernel_launch(void* const* d_in, const int* in_sizes, int n_in,
                              void* d_out, int out_size, void* d_ws, size_t ws_size,
                              hipStream_t stream) {
    const float* data   = (const float*)d_in[0];
    const float* weight = (const float*)d_in[1];
    const float* gamma  = (const float*)d_in[2];
    const float* beta   = (const float*)d_in[3];
    const int*   idx5   = (const int*)d_in[4];
    const int*   idx4   = (const int*)d_in[5];

    const int n_i5 = in_sizes[4];        // 65536 pool1 groups (children at depth 5)
    const int n_i4 = in_sizes[5];        // 16384 pool2 groups = pooled rows at depth 4
    const int G2   = n_i4;
    const int n5   = 8 * n_i4;           // nnum5 = 131072 level-5 slots
    const int rows = out_size / COUT;    // nnum4 = 32768
    const int M    = G2;                 // GEMM rows

    // workspace layout
    char* w = (char*)d_ws;
    float* P       = (float*)w;                         w += (size_t)G2 * CIN * sizeof(float);     // 16 MiB
    float* H       = (float*)w;                         w += (size_t)G2 * COUT * sizeof(float);    // 32 MiB
    const int NPART = 256;
    float* partial = (float*)w;                         w += (size_t)NPART * 1024 * sizeof(float); // 1 MiB
    float* scale   = (float*)w;                         w += COUT * sizeof(float);
    float* shift   = (float*)w;                         w += COUT * sizeof(float);
    int*   inv5    = (int*)w;                           w += (size_t)n5 * sizeof(int);             // 512 KiB
    int*   inv4    = (int*)w;                           w += (size_t)rows * sizeof(int);           // 128 KiB

    // 1. init inverse maps
    {
        int n = n5 > rows ? n5 : rows;
        init_kernel<<<(n + 255) / 256, 256, 0, stream>>>(inv5, n5, inv4, rows);
    }
    // 2. scatter inverse maps
    {
        int n = n_i5 > n_i4 ? n_i5 : n_i4;
        scatter_inv_kernel<<<(n + 255) / 256, 256, 0, stream>>>(idx5, n_i5, idx4, n_i4, inv5, inv4);
    }
    // 3. fused double max-pool: data -> P [G2][256]
    pool2_kernel<<<(G2 * 64 + 255) / 256, 256, 0, stream>>>(data, inv5, P, G2);
    // 4. GEMM: H = P @ W^T  [M][512]
    {
        dim3 grid(M / BM, COUT / BN);
        gemm_kernel<<<grid, 256, 0, stream>>>(P, weight, H, M);
    }
    // 5. column stats (deterministic two-stage)
    stats_partial_kernel<<<NPART, 256, 0, stream>>>(H, M / NPART, partial);
    bn_finalize_kernel<<<2, 256, 0, stream>>>(partial, NPART, gamma, beta, scale, shift,
                                              1.0f / (float)rows);
    // 6. normalize + relu + scatter into padded output
    out_kernel<<<((size_t)rows * 128 + 255) / 256, 256, 0, stream>>>(H, inv4, scale, shift,
                                                                     (float*)d_out, rows);
}

// Round 2
// 236.336 us; speedup vs baseline: 1.2065x; 1.2065x over previous
//
#include <hip/hip_runtime.h>
#include <hip/hip_bf16.h>
#include <math.h>

#define CIN 256
#define COUT 512

typedef __attribute__((ext_vector_type(8))) short bf16x8;
typedef __attribute__((ext_vector_type(4))) float f32x4;

__device__ __forceinline__ ushort f2bf(float f) {
    union { float f; unsigned u; } x; x.f = f;
    unsigned r = x.u + 0x7FFFu + ((x.u >> 16) & 1u);   // round-to-nearest-even
    return (ushort)(r >> 16);
}

// ---------------------------------------------------------------------------
// init: inv5[n5] = -1, inv4[n4] = -1
// ---------------------------------------------------------------------------
__global__ __launch_bounds__(256) void init_kernel(int* inv5, int n5, int* inv4, int n4) {
    int i = blockIdx.x * blockDim.x + threadIdx.x;
    if (i < n5) inv5[i] = -1;
    if (i < n4) inv4[i] = -1;
}

// ---------------------------------------------------------------------------
// scatter inverse maps
// ---------------------------------------------------------------------------
__global__ __launch_bounds__(256) void scatter_inv_kernel(const int* __restrict__ idx5, int n_i5,
                                                          const int* __restrict__ idx4, int n_i4,
                                                          int* __restrict__ inv5, int* __restrict__ inv4) {
    int i = blockIdx.x * blockDim.x + threadIdx.x;
    if (i < n_i5) inv5[idx5[i]] = i;
    if (i < n_i4) inv4[idx4[i]] = i;
}

// ---------------------------------------------------------------------------
// Fused double max-pool -> bf16 P.
// One wave per depth-4 group; lane q handles columns 4q..4q+3.
// Reads each data row exactly once (512 MiB), coalesced float4; writes bf16.
// ---------------------------------------------------------------------------
__global__ __launch_bounds__(256) void pool2_kernel(const float* __restrict__ data,
                                                    const int* __restrict__ inv5,
                                                    ushort* __restrict__ P, int G2) {
    int t = blockIdx.x * blockDim.x + threadIdx.x;
    int g = t >> 6;
    int q = t & 63;
    if (g >= G2) return;

    float4 acc = make_float4(-INFINITY, -INFINITY, -INFINITY, -INFINITY);
    bool any_empty = false;

    #pragma unroll
    for (int s = 0; s < 8; ++s) {
        int i = inv5[g * 8 + s];          // wave-uniform branch
        if (i >= 0) {
            const float* base = data + (size_t)i * 8 * CIN + q * 4;
            #pragma unroll
            for (int r = 0; r < 8; ++r) {
                float4 v = *reinterpret_cast<const float4*>(base + (size_t)r * CIN);
                acc.x = fmaxf(acc.x, v.x);
                acc.y = fmaxf(acc.y, v.y);
                acc.z = fmaxf(acc.z, v.z);
                acc.w = fmaxf(acc.w, v.w);
            }
        } else {
            any_empty = true;
        }
    }
    if (any_empty) {
        acc.x = fmaxf(acc.x, 0.f);
        acc.y = fmaxf(acc.y, 0.f);
        acc.z = fmaxf(acc.z, 0.f);
        acc.w = fmaxf(acc.w, 0.f);
    }
    ushort4 o;
    o.x = f2bf(acc.x); o.y = f2bf(acc.y); o.z = f2bf(acc.z); o.w = f2bf(acc.w);
    *reinterpret_cast<ushort4*>(&P[(size_t)g * CIN + q * 4]) = o;
}

// ---------------------------------------------------------------------------
// weight fp32 [512][256] -> bf16
// ---------------------------------------------------------------------------
__global__ __launch_bounds__(256) void wconv_kernel(const float* __restrict__ W,
                                                    ushort* __restrict__ Wb) {
    int i = (blockIdx.x * 256 + threadIdx.x) * 4;
    float4 v = *reinterpret_cast<const float4*>(W + i);
    ushort4 o;
    o.x = f2bf(v.x); o.y = f2bf(v.y); o.z = f2bf(v.z); o.w = f2bf(v.w);
    *reinterpret_cast<ushort4*>(&Wb[i]) = o;
}

// ---------------------------------------------------------------------------
// bf16 MFMA GEMM: H[m][n] = sum_k P[m][k]*W[n][k], fp32 out.
// 128x128 tile / block, 256 threads (2x2 waves, 64x64 per wave, 4x4 frags).
// LDS tiles [128][64] bf16 with XOR slot-swizzle (slot ^= row&7) -> 2-way max.
// ---------------------------------------------------------------------------
__global__ __launch_bounds__(256) void mfma_gemm_kernel(const ushort* __restrict__ A,
                                                        const ushort* __restrict__ B,
                                                        float* __restrict__ H) {
    __shared__ __align__(16) ushort Asm[128 * 64];
    __shared__ __align__(16) ushort Bsm[128 * 64];

    int t = threadIdx.x;
    int lane = t & 63;
    int wid = t >> 6;
    int wm = wid >> 1, wn = wid & 1;
    int m0 = blockIdx.x * 128, n0 = blockIdx.y * 128;

    f32x4 acc[4][4] = {};

    for (int k0 = 0; k0 < CIN; k0 += 64) {
        // stage A,B tiles: 1024 16-B chunks each, swizzled ds_write
        #pragma unroll
        for (int i = 0; i < 4; ++i) {
            int idx = i * 256 + t;          // 0..1023
            int row = idx >> 3;
            int sl  = idx & 7;              // logical 8-elem slot
            bf16x8 av = *reinterpret_cast<const bf16x8*>(A + (size_t)(m0 + row) * CIN + k0 + sl * 8);
            bf16x8 bv = *reinterpret_cast<const bf16x8*>(B + (size_t)(n0 + row) * CIN + k0 + sl * 8);
            int ws = (sl ^ (row & 7)) * 8;
            *reinterpret_cast<bf16x8*>(&Asm[row * 64 + ws]) = av;
            *reinterpret_cast<bf16x8*>(&Bsm[row * 64 + ws]) = bv;
        }
        __syncthreads();

        #pragma unroll
        for (int ks = 0; ks < 2; ++ks) {
            bf16x8 af[4], bfr[4];
            int slog = ks * 4 + (lane >> 4);
            #pragma unroll
            for (int mi = 0; mi < 4; ++mi) {
                int row = wm * 64 + mi * 16 + (lane & 15);
                af[mi] = *reinterpret_cast<const bf16x8*>(&Asm[row * 64 + (slog ^ (row & 7)) * 8]);
            }
            #pragma unroll
            for (int ni = 0; ni < 4; ++ni) {
                int col = wn * 64 + ni * 16 + (lane & 15);
                bfr[ni] = *reinterpret_cast<const bf16x8*>(&Bsm[col * 64 + (slog ^ (col & 7)) * 8]);
            }
            #pragma unroll
            for (int mi = 0; mi < 4; ++mi)
                #pragma unroll
                for (int ni = 0; ni < 4; ++ni)
                    acc[mi][ni] = __builtin_amdgcn_mfma_f32_16x16x32_bf16(af[mi], bfr[ni], acc[mi][ni], 0, 0, 0);
        }
        __syncthreads();
    }

    // epilogue: C/D layout col=lane&15, row=(lane>>4)*4+reg
    #pragma unroll
    for (int mi = 0; mi < 4; ++mi) {
        #pragma unroll
        for (int ni = 0; ni < 4; ++ni) {
            int col   = n0 + wn * 64 + ni * 16 + (lane & 15);
            int rbase = m0 + wm * 64 + mi * 16 + (lane >> 4) * 4;
            #pragma unroll
            for (int r = 0; r < 4; ++r)
                H[(size_t)(rbase + r) * COUT + col] = acc[mi][ni][r];
        }
    }
}

// ---------------------------------------------------------------------------
// Deterministic column stats, stage 1
// ---------------------------------------------------------------------------
__global__ __launch_bounds__(256) void stats_partial_kernel(const float* __restrict__ H,
                                                            int rows_per_block,
                                                            float* __restrict__ partial) {
    int b = blockIdx.x;
    int c0 = threadIdx.x * 2;
    float s0 = 0.f, s1 = 0.f, q0 = 0.f, q1 = 0.f;
    size_t r0 = (size_t)b * rows_per_block;
    for (int r = 0; r < rows_per_block; ++r) {
        float2 v = *reinterpret_cast<const float2*>(&H[(r0 + r) * COUT + c0]);
        s0 += v.x; q0 = fmaf(v.x, v.x, q0);
        s1 += v.y; q1 = fmaf(v.y, v.y, q1);
    }
    float* pb = partial + (size_t)b * 1024;
    pb[c0]           = s0;
    pb[c0 + 1]       = s1;
    pb[512 + c0]     = q0;
    pb[512 + c0 + 1] = q1;
}

// ---------------------------------------------------------------------------
// Stage 2: finalize BN scale/shift
// ---------------------------------------------------------------------------
__global__ __launch_bounds__(256) void bn_finalize_kernel(const float* __restrict__ partial, int nparts,
                                                          const float* __restrict__ gamma,
                                                          const float* __restrict__ beta,
                                                          float* __restrict__ scale,
                                                          float* __restrict__ shift,
                                                          float invN) {
    int c = blockIdx.x * blockDim.x + threadIdx.x;
    if (c >= COUT) return;
    float s = 0.f, q = 0.f;
    for (int p = 0; p < nparts; ++p) {
        s += partial[(size_t)p * 1024 + c];
        q += partial[(size_t)p * 1024 + 512 + c];
    }
    float mean = s * invN;
    float var  = fmaf(q, invN, -mean * mean);
    float inv  = rsqrtf(var + 1e-5f);
    float sc   = gamma[c] * inv;
    scale[c] = sc;
    shift[c] = fmaf(-mean, sc, beta[c]);
}

// ---------------------------------------------------------------------------
// Final: normalize + relu + scatter
// ---------------------------------------------------------------------------
__global__ __launch_bounds__(256) void out_kernel(const float* __restrict__ H,
                                                  const int* __restrict__ inv4,
                                                  const float* __restrict__ scale,
                                                  const float* __restrict__ shift,
                                                  float* __restrict__ out, int rows) {
    int t = blockIdx.x * blockDim.x + threadIdx.x;
    int m = t >> 7;
    int q = t & 127;
    if (m >= rows) return;
    int c = q * 4;
    int j = inv4[m];
    float4 sc = *reinterpret_cast<const float4*>(&scale[c]);
    float4 sh = *reinterpret_cast<const float4*>(&shift[c]);
    float4 r;
    if (j >= 0) {
        float4 h = *reinterpret_cast<const float4*>(&H[(size_t)j * COUT + c]);
        r.x = fmaxf(fmaf(h.x, sc.x, sh.x), 0.f);
        r.y = fmaxf(fmaf(h.y, sc.y, sh.y), 0.f);
        r.z = fmaxf(fmaf(h.z, sc.z, sh.z), 0.f);
        r.w = fmaxf(fmaf(h.w, sc.w, sh.w), 0.f);
    } else {
        r.x = fmaxf(sh.x, 0.f);
        r.y = fmaxf(sh.y, 0.f);
        r.z = fmaxf(sh.z, 0.f);
        r.w = fmaxf(sh.w, 0.f);
    }
    *reinterpret_cast<float4*>(&out[(size_t)m * COUT + c]) = r;
}

// ---------------------------------------------------------------------------
extern "C" void kernel_launch(void* const* d_in, const int* in_sizes, int n_in,
                              void* d_out, int out_size, void* d_ws, size_t ws_size,
                              hipStream_t stream) {
    const float* data   = (const float*)d_in[0];
    const float* weight = (const float*)d_in[1];
    const float* gamma  = (const float*)d_in[2];
    const float* beta   = (const float*)d_in[3];
    const int*   idx5   = (const int*)d_in[4];
    const int*   idx4   = (const int*)d_in[5];

    const int n_i5 = in_sizes[4];        // 65536
    const int n_i4 = in_sizes[5];        // 16384
    const int G2   = n_i4;
    const int n5   = 8 * n_i4;           // 131072
    const int rows = out_size / COUT;    // 32768
    const int M    = G2;                 // 16384

    // workspace layout
    char* w = (char*)d_ws;
    ushort* P      = (ushort*)w;                        w += (size_t)G2 * CIN * sizeof(ushort);    // 8 MiB
    float*  H      = (float*)w;                         w += (size_t)G2 * COUT * sizeof(float);    // 32 MiB
    ushort* Wb     = (ushort*)w;                        w += (size_t)COUT * CIN * sizeof(ushort);  // 0.25 MiB
    const int NPART = 256;
    float* partial = (float*)w;                         w += (size_t)NPART * 1024 * sizeof(float); // 1 MiB
    float* scale   = (float*)w;                         w += COUT * sizeof(float);
    float* shift   = (float*)w;                         w += COUT * sizeof(float);
    int*   inv5    = (int*)w;                           w += (size_t)n5 * sizeof(int);             // 512 KiB
    int*   inv4    = (int*)w;                           w += (size_t)rows * sizeof(int);           // 128 KiB

    // 1. init inverse maps
    {
        int n = n5 > rows ? n5 : rows;
        init_kernel<<<(n + 255) / 256, 256, 0, stream>>>(inv5, n5, inv4, rows);
    }
    // 2. scatter inverse maps
    {
        int n = n_i5 > n_i4 ? n_i5 : n_i4;
        scatter_inv_kernel<<<(n + 255) / 256, 256, 0, stream>>>(idx5, n_i5, idx4, n_i4, inv5, inv4);
    }
    // 2b. weight -> bf16 (independent of 1-3, overlaps in-order just fine)
    wconv_kernel<<<(COUT * CIN / 4 + 255) / 256, 256, 0, stream>>>(weight, Wb);
    // 3. fused double max-pool -> bf16 P [G2][256]
    pool2_kernel<<<(G2 * 64 + 255) / 256, 256, 0, stream>>>(data, inv5, P, G2);
    // 4. MFMA GEMM: H = P @ Wb^T  [M][512] fp32
    {
        dim3 grid(M / 128, COUT / 128);
        mfma_gemm_kernel<<<grid, 256, 0, stream>>>(P, Wb, H);
    }
    // 5. column stats (deterministic two-stage)
    stats_partial_kernel<<<NPART, 256, 0, stream>>>(H, M / NPART, partial);
    bn_finalize_kernel<<<2, 256, 0, stream>>>(partial, NPART, gamma, beta, scale, shift,
                                              1.0f / (float)rows);
    // 6. normalize + relu + scatter into padded output
    out_kernel<<<((size_t)rows * 128 + 255) / 256, 256, 0, stream>>>(H, inv4, scale, shift,
                                                                     (float*)d_out, rows);
}

// Round 3
// 155.854 us; speedup vs baseline: 1.8295x; 1.5164x over previous
//
#include <hip/hip_runtime.h>
#include <hip/hip_bf16.h>
#include <math.h>

#define CIN 256
#define COUT 512

typedef __attribute__((ext_vector_type(8))) short bf16x8;
typedef __attribute__((ext_vector_type(4))) float f32x4;
typedef __attribute__((ext_vector_type(4))) float f32x4v;

__device__ __forceinline__ ushort f2bf(float f) {
    union { float f; unsigned u; } x; x.f = f;
    unsigned r = x.u + 0x7FFFu + ((x.u >> 16) & 1u);   // round-to-nearest-even
    return (ushort)(r >> 16);
}
__device__ __forceinline__ float bf2f(ushort u) {
    union { unsigned u; float f; } x; x.u = (unsigned)u << 16; return x.f;
}

// ---------------------------------------------------------------------------
// prep: build inv5/inv4 (scatter + gap-fill from sorted unique idx arrays,
// race-free: thread i owns [idx[i], idx[i+1]) ) and convert weight -> bf16.
// ---------------------------------------------------------------------------
__global__ __launch_bounds__(256) void prep_kernel(const int* __restrict__ idx5, int n_i5,
                                                   const int* __restrict__ idx4, int n_i4,
                                                   int n5, int n4,
                                                   int* __restrict__ inv5, int* __restrict__ inv4,
                                                   const float* __restrict__ W,
                                                   ushort* __restrict__ Wb, int wquads) {
    int t = blockIdx.x * blockDim.x + threadIdx.x;
    if (t < n_i5) {
        int s = idx5[t];
        inv5[s] = t;
        int e = (t + 1 < n_i5) ? idx5[t + 1] : n5;
        for (int k = s + 1; k < e; ++k) inv5[k] = -1;
        if (t == 0) for (int k = 0; k < s; ++k) inv5[k] = -1;
    } else if (t < n_i5 + n_i4) {
        int i = t - n_i5;
        int s = idx4[i];
        inv4[s] = i;
        int e = (i + 1 < n_i4) ? idx4[i + 1] : n4;
        for (int k = s + 1; k < e; ++k) inv4[k] = -1;
        if (i == 0) for (int k = 0; k < s; ++k) inv4[k] = -1;
    } else if (t < n_i5 + n_i4 + wquads) {
        int i = (t - n_i5 - n_i4) * 4;
        float4 v = *reinterpret_cast<const float4*>(W + i);
        ushort4 o;
        o.x = f2bf(v.x); o.y = f2bf(v.y); o.z = f2bf(v.z); o.w = f2bf(v.w);
        *reinterpret_cast<ushort4*>(&Wb[i]) = o;
    }
}

// ---------------------------------------------------------------------------
// Fused double max-pool -> bf16 P.
// One wave per depth-4 group; lane q handles columns 4q..4q+3.
// Streams each data row exactly once (512 MiB), nontemporal float4.
// ---------------------------------------------------------------------------
__global__ __launch_bounds__(256) void pool2_kernel(const float* __restrict__ data,
                                                    const int* __restrict__ inv5,
                                                    ushort* __restrict__ P, int G2) {
    int t = blockIdx.x * blockDim.x + threadIdx.x;
    int g = t >> 6;          // wave-uniform
    int q = t & 63;
    if (g >= G2) return;

    float4 acc = make_float4(-INFINITY, -INFINITY, -INFINITY, -INFINITY);
    bool any_empty = false;

    #pragma unroll
    for (int s = 0; s < 8; ++s) {
        int i = inv5[g * 8 + s];
        i = __builtin_amdgcn_readfirstlane(i);     // scalarize: branch + base addr in SGPR
        if (i >= 0) {
            const float* base = data + (size_t)i * 8 * CIN + q * 4;
            #pragma unroll
            for (int r = 0; r < 8; ++r) {
                f32x4v v = __builtin_nontemporal_load(
                    reinterpret_cast<const f32x4v*>(base + (size_t)r * CIN));
                acc.x = fmaxf(acc.x, v.x);
                acc.y = fmaxf(acc.y, v.y);
                acc.z = fmaxf(acc.z, v.z);
                acc.w = fmaxf(acc.w, v.w);
            }
        } else {
            any_empty = true;
        }
    }
    if (any_empty) {
        acc.x = fmaxf(acc.x, 0.f);
        acc.y = fmaxf(acc.y, 0.f);
        acc.z = fmaxf(acc.z, 0.f);
        acc.w = fmaxf(acc.w, 0.f);
    }
    ushort4 o;
    o.x = f2bf(acc.x); o.y = f2bf(acc.y); o.z = f2bf(acc.z); o.w = f2bf(acc.w);
    *reinterpret_cast<ushort4*>(&P[(size_t)g * CIN + q * 4]) = o;
}

// ---------------------------------------------------------------------------
// bf16 MFMA GEMM + fused column stats.
// 128x128 tile / block, 256 threads (2x2 waves, 64x64/wave, 4x4 frags).
// LDS [128][64] bf16, XOR slot-swizzle (slot ^= row&7) -> 2-way max (free).
// Epilogue: per-block column sum/sumsq partials (deterministic shfl+LDS
// reduction) -> partial[bm][1024]; H written as bf16.
// ---------------------------------------------------------------------------
__global__ __launch_bounds__(256) void mfma_gemm_kernel(const ushort* __restrict__ A,
                                                        const ushort* __restrict__ B,
                                                        ushort* __restrict__ H,
                                                        float* __restrict__ partial) {
    __shared__ __align__(16) ushort Asm[128 * 64];
    __shared__ __align__(16) ushort Bsm[128 * 64];

    int t = threadIdx.x;
    int lane = t & 63;
    int wid = t >> 6;
    int wm = wid >> 1, wn = wid & 1;
    int m0 = blockIdx.x * 128, n0 = blockIdx.y * 128;

    f32x4 acc[4][4] = {};

    for (int k0 = 0; k0 < CIN; k0 += 64) {
        #pragma unroll
        for (int i = 0; i < 4; ++i) {
            int idx = i * 256 + t;          // 0..1023
            int row = idx >> 3;
            int sl  = idx & 7;
            bf16x8 av = *reinterpret_cast<const bf16x8*>(A + (size_t)(m0 + row) * CIN + k0 + sl * 8);
            bf16x8 bv = *reinterpret_cast<const bf16x8*>(B + (size_t)(n0 + row) * CIN + k0 + sl * 8);
            int ws = (sl ^ (row & 7)) * 8;
            *reinterpret_cast<bf16x8*>(&Asm[row * 64 + ws]) = av;
            *reinterpret_cast<bf16x8*>(&Bsm[row * 64 + ws]) = bv;
        }
        __syncthreads();

        #pragma unroll
        for (int ks = 0; ks < 2; ++ks) {
            bf16x8 af[4], bfr[4];
            int slog = ks * 4 + (lane >> 4);
            #pragma unroll
            for (int mi = 0; mi < 4; ++mi) {
                int row = wm * 64 + mi * 16 + (lane & 15);
                af[mi] = *reinterpret_cast<const bf16x8*>(&Asm[row * 64 + (slog ^ (row & 7)) * 8]);
            }
            #pragma unroll
            for (int ni = 0; ni < 4; ++ni) {
                int col = wn * 64 + ni * 16 + (lane & 15);
                bfr[ni] = *reinterpret_cast<const bf16x8*>(&Bsm[col * 64 + (slog ^ (col & 7)) * 8]);
            }
            #pragma unroll
            for (int mi = 0; mi < 4; ++mi)
                #pragma unroll
                for (int ni = 0; ni < 4; ++ni)
                    acc[mi][ni] = __builtin_amdgcn_mfma_f32_16x16x32_bf16(af[mi], bfr[ni], acc[mi][ni], 0, 0, 0);
        }
        __syncthreads();
    }

    // ---- fused column stats: per-lane -> shfl across row-quads -> LDS across wm
    float s[4], q[4];
    #pragma unroll
    for (int ni = 0; ni < 4; ++ni) {
        s[ni] = 0.f; q[ni] = 0.f;
        #pragma unroll
        for (int mi = 0; mi < 4; ++mi)
            #pragma unroll
            for (int r = 0; r < 4; ++r) {
                float v = acc[mi][ni][r];
                s[ni] += v;
                q[ni] = fmaf(v, v, q[ni]);
            }
        s[ni] += __shfl_xor(s[ni], 16);
        s[ni] += __shfl_xor(s[ni], 32);
        q[ni] += __shfl_xor(q[ni], 16);
        q[ni] += __shfl_xor(q[ni], 32);
    }
    float* redS = (float*)Asm;        // reuse LDS: [2][128] sums, [2][128] sq
    float* redQ = redS + 256;
    if (lane < 16) {
        #pragma unroll
        for (int ni = 0; ni < 4; ++ni) {
            int c = wn * 64 + ni * 16 + lane;
            redS[wm * 128 + c] = s[ni];
            redQ[wm * 128 + c] = q[ni];
        }
    }
    __syncthreads();
    if (t < 128) {
        float S = redS[t] + redS[128 + t];
        float Q = redQ[t] + redQ[128 + t];
        partial[(size_t)blockIdx.x * 1024 + blockIdx.y * 128 + t]       = S;
        partial[(size_t)blockIdx.x * 1024 + 512 + blockIdx.y * 128 + t] = Q;
    }

    // ---- H write (bf16)
    #pragma unroll
    for (int mi = 0; mi < 4; ++mi) {
        #pragma unroll
        for (int ni = 0; ni < 4; ++ni) {
            int col   = n0 + wn * 64 + ni * 16 + (lane & 15);
            int rbase = m0 + wm * 64 + mi * 16 + (lane >> 4) * 4;
            #pragma unroll
            for (int r = 0; r < 4; ++r)
                H[(size_t)(rbase + r) * COUT + col] = f2bf(acc[mi][ni][r]);
        }
    }
}

// ---------------------------------------------------------------------------
// finalize BN scale/shift from the 128 per-m-block partials
// ---------------------------------------------------------------------------
__global__ __launch_bounds__(256) void bn_finalize_kernel(const float* __restrict__ partial, int nparts,
                                                          const float* __restrict__ gamma,
                                                          const float* __restrict__ beta,
                                                          float* __restrict__ scale,
                                                          float* __restrict__ shift,
                                                          float invN) {
    int c = blockIdx.x * blockDim.x + threadIdx.x;
    if (c >= COUT) return;
    float s = 0.f, q = 0.f;
    for (int p = 0; p < nparts; ++p) {
        s += partial[(size_t)p * 1024 + c];
        q += partial[(size_t)p * 1024 + 512 + c];
    }
    float mean = s * invN;
    float var  = fmaf(q, invN, -mean * mean);
    float inv  = rsqrtf(var + 1e-5f);
    float sc   = gamma[c] * inv;
    scale[c] = sc;
    shift[c] = fmaf(-mean, sc, beta[c]);
}

// ---------------------------------------------------------------------------
// Final: normalize + relu + scatter (H is bf16)
// ---------------------------------------------------------------------------
__global__ __launch_bounds__(256) void out_kernel(const ushort* __restrict__ H,
                                                  const int* __restrict__ inv4,
                                                  const float* __restrict__ scale,
                                                  const float* __restrict__ shift,
                                                  float* __restrict__ out, int rows) {
    int t = blockIdx.x * blockDim.x + threadIdx.x;
    int m = t >> 7;
    int qd = t & 127;
    if (m >= rows) return;
    int c = qd * 4;
    int j = inv4[m];
    float4 sc = *reinterpret_cast<const float4*>(&scale[c]);
    float4 sh = *reinterpret_cast<const float4*>(&shift[c]);
    float4 r;
    if (j >= 0) {
        ushort4 h = *reinterpret_cast<const ushort4*>(&H[(size_t)j * COUT + c]);
        r.x = fmaxf(fmaf(bf2f(h.x), sc.x, sh.x), 0.f);
        r.y = fmaxf(fmaf(bf2f(h.y), sc.y, sh.y), 0.f);
        r.z = fmaxf(fmaf(bf2f(h.z), sc.z, sh.z), 0.f);
        r.w = fmaxf(fmaf(bf2f(h.w), sc.w, sh.w), 0.f);
    } else {
        r.x = fmaxf(sh.x, 0.f);
        r.y = fmaxf(sh.y, 0.f);
        r.z = fmaxf(sh.z, 0.f);
        r.w = fmaxf(sh.w, 0.f);
    }
    *reinterpret_cast<float4*>(&out[(size_t)m * COUT + c]) = r;
}

// ---------------------------------------------------------------------------
extern "C" void kernel_launch(void* const* d_in, const int* in_sizes, int n_in,
                              void* d_out, int out_size, void* d_ws, size_t ws_size,
                              hipStream_t stream) {
    const float* data   = (const float*)d_in[0];
    const float* weight = (const float*)d_in[1];
    const float* gamma  = (const float*)d_in[2];
    const float* beta   = (const float*)d_in[3];
    const int*   idx5   = (const int*)d_in[4];
    const int*   idx4   = (const int*)d_in[5];

    const int n_i5 = in_sizes[4];        // 65536
    const int n_i4 = in_sizes[5];        // 16384
    const int G2   = n_i4;
    const int n5   = 8 * n_i4;           // 131072
    const int rows = out_size / COUT;    // 32768
    const int M    = G2;                 // 16384
    const int MB   = M / 128;            // 128 m-tiles

    // workspace layout
    char* w = (char*)d_ws;
    ushort* P      = (ushort*)w;                        w += (size_t)G2 * CIN * sizeof(ushort);    // 8 MiB
    ushort* H      = (ushort*)w;                        w += (size_t)G2 * COUT * sizeof(ushort);   // 16 MiB
    ushort* Wb     = (ushort*)w;                        w += (size_t)COUT * CIN * sizeof(ushort);  // 0.25 MiB
    float* partial = (float*)w;                         w += (size_t)MB * 1024 * sizeof(float);    // 512 KiB
    float* scale   = (float*)w;                         w += COUT * sizeof(float);
    float* shift   = (float*)w;                         w += COUT * sizeof(float);
    int*   inv5    = (int*)w;                           w += (size_t)n5 * sizeof(int);             // 512 KiB
    int*   inv4    = (int*)w;                           w += (size_t)rows * sizeof(int);           // 128 KiB

    const int wquads = COUT * CIN / 4;   // 32768

    // 1. prep: inverse maps + weight->bf16 (one kernel, race-free gap-fill)
    {
        int n = n_i5 + n_i4 + wquads;    // 114688
        prep_kernel<<<(n + 255) / 256, 256, 0, stream>>>(idx5, n_i5, idx4, n_i4, n5, rows,
                                                         inv5, inv4, weight, Wb, wquads);
    }
    // 2. fused double max-pool -> bf16 P [G2][256]
    pool2_kernel<<<(G2 * 64 + 255) / 256, 256, 0, stream>>>(data, inv5, P, G2);
    // 3. MFMA GEMM + fused stats: H(bf16) = P @ Wb^T, partial[bm][...]
    {
        dim3 grid(MB, COUT / 128);
        mfma_gemm_kernel<<<grid, 256, 0, stream>>>(P, Wb, H, partial);
    }
    // 4. finalize BN scale/shift
    bn_finalize_kernel<<<2, 256, 0, stream>>>(partial, MB, gamma, beta, scale, shift,
                                              1.0f / (float)rows);
    // 5. normalize + relu + scatter into padded output
    out_kernel<<<((size_t)rows * 128 + 255) / 256, 256, 0, stream>>>(H, inv4, scale, shift,
                                                                     (float*)d_out, rows);
}